// Round 18
// baseline (91.464 us; speedup 1.0000x reference)
//
#include <hip/hip_runtime.h>
#include <math.h>

#define NPTS 8192
#define KNN 32
#define NITEMS (NPTS / 8)

typedef unsigned int uint;
typedef unsigned long long u64;
typedef float v2f __attribute__((ext_vector_type(2)));

#if __has_builtin(__builtin_elementwise_fma)
__device__ __forceinline__ v2f fma2(v2f a, v2f b, v2f c) {
    return __builtin_elementwise_fma(a, b, c);
}
#else
__device__ __forceinline__ v2f fma2(v2f a, v2f b, v2f c) {
    v2f r; r.x = fmaf(a.x, b.x, c.x); r.y = fmaf(a.y, b.y, c.y); return r;
}
#endif
#if __has_builtin(__builtin_elementwise_min)
__device__ __forceinline__ v2f min2(v2f a, v2f b) {
    return __builtin_elementwise_min(a, b);
}
#else
__device__ __forceinline__ v2f min2(v2f a, v2f b) {
    v2f r; r.x = fminf(a.x, b.x); r.y = fminf(a.y, b.y); return r;
}
#endif
__device__ __forceinline__ v2f mk2(float a, float b) { v2f r; r.x = a; r.y = b; return r; }

// ---- workspace layout (bytes) ----
#define OFF_PTS4 0                      // float4[N]            131072
#define OFF_CTR  131072                 // uint work-queue counter (reset each launch by prep)
#define OFF_WQ   147968                 // float[128*3]         1536  (Wf_pc@Wpc)
#define OFF_BQ   149504                 // float[128]           512   (Wf_pc@bpc+bf)
#define OFF_G    150016                 // float[N*128]         4194304
#define OFF_F    5392896                // float[N*128] row-major sur only 4194304

__device__ __forceinline__ uint fkey(float d) {
    uint bits = __float_as_uint(d);
    return bits ^ (0x80000000u | (uint)((int)bits >> 31));  // monotone sortable
}
__device__ __forceinline__ float finv(uint key) {
    uint bits = (key & 0x80000000u) ? (key ^ 0x80000000u) : ~key;
    return __uint_as_float(bits);
}
__device__ __forceinline__ uint mbcnt64(u64 m) {
    uint lo = __builtin_amdgcn_mbcnt_lo((uint)m, 0u);
    return __builtin_amdgcn_mbcnt_hi((uint)(m >> 32), lo);
}

// ---------------------------------------------------------------------------
// ONE preprocessing kernel, zero intra-kernel dependencies:
//   blocks 0..31   : pts4 = (x,y,z,|p|^2)
//   block  32      : Wq/bq collapse + work-queue counter reset (for k_knn)
//   blocks 33..544 : g[n][:] two-stage from raw W1/b1/W2/b2 (16 points/block)
__launch_bounds__(256)
__global__ void k_prep_gfeat(const float* __restrict__ cloud, const float* __restrict__ img_feat,
                             const float* __restrict__ W1, const float* __restrict__ b1,
                             const float* __restrict__ W2, const float* __restrict__ b2,
                             const float* __restrict__ Wp1, const float* __restrict__ bp1,
                             const float* __restrict__ Wp2, const float* __restrict__ bp2,
                             const float* __restrict__ Wf, const float* __restrict__ bf,
                             float4* __restrict__ pts4, float* __restrict__ Wq,
                             float* __restrict__ bq, float* __restrict__ g,
                             uint* __restrict__ ctr) {
    int bid = blockIdx.x;
    int t = threadIdx.x;
    if (bid < 32) {
        int n = bid * 256 + t;
        float x = cloud[n * 3 + 0], y = cloud[n * 3 + 1], z = cloud[n * 3 + 2];
        float sq = fmaf(x, x, fmaf(y, y, z * z));
        pts4[n] = make_float4(x, y, z, sq);
        return;
    }
    if (bid == 32) {
        if (t == 0) *ctr = 0u;          // queue reset; k_knn is stream-ordered after
        __shared__ float wpcS[384];
        __shared__ float bpcS[128];
        for (int i = t; i < 384; i += 256) {
            int o = i / 3, c = i - o * 3;
            float a = 0.f;
            for (int u = 0; u < 64; ++u) a = fmaf(Wp2[o * 64 + u], Wp1[u * 3 + c], a);
            wpcS[i] = a;
        }
        if (t < 128) {
            float a = bp2[t];
            for (int u = 0; u < 64; ++u) a = fmaf(Wp2[t * 64 + u], bp1[u], a);
            bpcS[t] = a;
        }
        __syncthreads();
        for (int i = t; i < 384; i += 256) {
            int d = i / 3, c = i - d * 3;
            float a = 0.f;
            for (int o = 0; o < 128; ++o) a = fmaf(Wf[d * 256 + 128 + o], wpcS[o * 3 + c], a);
            Wq[i] = a;
        }
        if (t < 128) {
            float a = bf[t];
            for (int o = 0; o < 128; ++o) a = fmaf(Wf[t * 256 + 128 + o], bpcS[o], a);
            bq[t] = a;
        }
        return;
    }
    // ---- gfeat: 16 points, two-stage; W2 staged into LDS (coalesced) with
    // XOR-swizzled float4 blocks so stage-2 row reads are ds_read_b128.
    {
        __shared__ float ftT[16][36];   // [n][c]
        __shared__ float hS[16][68];    // [n][o]
        __shared__ float w2S[128 * 64]; // [d][og^...]   32 KB
        int n0 = (bid - 33) * 16;

        if (t < 128) {                  // 32c x 16n, one float4 per thread
            int c = t >> 2, ng = (t & 3) * 4;
            float4 v = *(const float4*)&img_feat[c * NPTS + n0 + ng];
            ftT[ng + 0][c] = v.x; ftT[ng + 1][c] = v.y;
            ftT[ng + 2][c] = v.z; ftT[ng + 3][c] = v.w;
        }
        {   // W2 bounce: 2048 float4, coalesced global, swizzled LDS
            const float4* W2v = (const float4*)W2;
            for (int i = t; i < 2048; i += 256) {
                float4 v = W2v[i];
                int dd = i >> 4, og = i & 15;
                *(float4*)&w2S[dd * 64 + ((og ^ (dd & 15)) << 2)] = v;
            }
        }
        __syncthreads();

        // stage 1: h[n][o] = b1[o] + sum_c W1[o][c] * ft[n][c]
        {
            int n = t & 15, ob = t >> 4;           // ob in 0..15
            v2f fr[16];
#pragma unroll
            for (int c4 = 0; c4 < 8; ++c4) {
                float4 fv = *(const float4*)&ftT[n][c4 * 4];
                fr[2 * c4 + 0] = mk2(fv.x, fv.y);
                fr[2 * c4 + 1] = mk2(fv.z, fv.w);
            }
#pragma unroll
            for (int r = 0; r < 4; ++r) {
                int o = ob + r * 16;
                v2f acc = mk2(b1[o], 0.f);
                const float4* w1r = (const float4*)&W1[o * 32];
#pragma unroll
                for (int c4 = 0; c4 < 8; ++c4) {
                    float4 wv = w1r[c4];
                    acc = fma2(mk2(wv.x, wv.y), fr[2 * c4 + 0], acc);
                    acc = fma2(mk2(wv.z, wv.w), fr[2 * c4 + 1], acc);
                }
                hS[n][o] = acc.x + acc.y;
            }
        }
        __syncthreads();

        // stage 2: g[n][d] = b2[d] + sum_o W2[d][o] * h[n][o]
        {
            int d = t & 127, grp = t >> 7;
            v2f w2r[32];
#pragma unroll
            for (int o4 = 0; o4 < 16; ++o4) {
                float4 wv = *(const float4*)&w2S[d * 64 + ((o4 ^ (d & 15)) << 2)];
                w2r[2 * o4 + 0] = mk2(wv.x, wv.y);
                w2r[2 * o4 + 1] = mk2(wv.z, wv.w);
            }
            float b2d = b2[d];
#pragma unroll
            for (int nl = grp * 8; nl < grp * 8 + 8; ++nl) {
                v2f acc = mk2(b2d, 0.f);
#pragma unroll
                for (int o4 = 0; o4 < 16; ++o4) {
                    float4 hv = *(const float4*)&hS[nl][o4 * 4];   // broadcast
                    acc = fma2(w2r[2 * o4 + 0], mk2(hv.x, hv.y), acc);
                    acc = fma2(w2r[2 * o4 + 1], mk2(hv.z, hv.w), acc);
                }
                g[(n0 + nl) * 128 + d] = acc.x + acc.y;
            }
        }
    }
}

// ---------------------------------------------------------------------------
// Exact KNN + fused surround branch, v7: PERSISTENT blocks + work-stealing.
// 1024 resident blocks (512 thr, 8 waves) pull 8-query items off a global
// atomic queue — fast blocks absorb block-runtime skew, eliminating the drain
// tail that capped occupancy at ~56% with the static 1:1 dispatch.
// Output is deterministic: each item depends only on its own read-only inputs.
// Per item: shared prepass + truncated threshold radix; 16-bit mask sweep;
// deterministic ballot compaction; exact radix select; fused epilogue.
#define CAPSEG 64
__launch_bounds__(512, 8)
__global__ void k_knn(const float4* __restrict__ pts4, const float* __restrict__ g,
                      float* __restrict__ F, uint* __restrict__ ctr) {
    __shared__ float pminS[8][512];           // [q][wave*64+lane]   16 KB
    __shared__ uint spillIdx[8][8][CAPSEG];   // [q][seg][slot]      16 KB
    __shared__ uint segcnt[8][8];             // [q][seg]
    __shared__ float Tsh[8];
    __shared__ uint2 selEJ[8][32];            // per query: (.x = e bits, .y = idx)
    __shared__ uint itemS;

    int t = threadIdx.x, w = t >> 6, lane = t & 63;

#define D8(P, S01, S23, S45, S67) { \
    v2f pw2 = mk2((P).w, (P).w), pz2 = mk2((P).z, (P).z); \
    v2f py2 = mk2((P).y, (P).y), px2 = mk2((P).x, (P).x); \
    S01 = qw01 + pw2; S01 = fma2(m2z01, pz2, S01); S01 = fma2(m2y01, py2, S01); S01 = fma2(m2x01, px2, S01); \
    S23 = qw23 + pw2; S23 = fma2(m2z23, pz2, S23); S23 = fma2(m2y23, py2, S23); S23 = fma2(m2x23, px2, S23); \
    S45 = qw45 + pw2; S45 = fma2(m2z45, pz2, S45); S45 = fma2(m2y45, py2, S45); S45 = fma2(m2x45, px2, S45); \
    S67 = qw67 + pw2; S67 = fma2(m2z67, pz2, S67); S67 = fma2(m2y67, py2, S67); S67 = fma2(m2x67, px2, S67); }

    for (;;) {
        if (t == 0) itemS = atomicAdd(ctr, 1u);
        __syncthreads();                       // broadcast item; guards LDS reuse
        uint item = itemS;
        if (item >= (uint)NITEMS) break;
        int qbase = (int)item * 8;

        float4 q0 = pts4[qbase + 0], q1 = pts4[qbase + 1], q2 = pts4[qbase + 2], q3 = pts4[qbase + 3];
        float4 q4 = pts4[qbase + 4], q5 = pts4[qbase + 5], q6 = pts4[qbase + 6], q7 = pts4[qbase + 7];
        float4 qq = pts4[qbase + w];           // own query

        v2f m2x01 = mk2(-2.f * q0.x, -2.f * q1.x), m2y01 = mk2(-2.f * q0.y, -2.f * q1.y);
        v2f m2z01 = mk2(-2.f * q0.z, -2.f * q1.z), qw01 = mk2(q0.w, q1.w);
        v2f m2x23 = mk2(-2.f * q2.x, -2.f * q3.x), m2y23 = mk2(-2.f * q2.y, -2.f * q3.y);
        v2f m2z23 = mk2(-2.f * q2.z, -2.f * q3.z), qw23 = mk2(q2.w, q3.w);
        v2f m2x45 = mk2(-2.f * q4.x, -2.f * q5.x), m2y45 = mk2(-2.f * q4.y, -2.f * q5.y);
        v2f m2z45 = mk2(-2.f * q4.z, -2.f * q5.z), qw45 = mk2(q4.w, q5.w);
        v2f m2x67 = mk2(-2.f * q6.x, -2.f * q7.x), m2y67 = mk2(-2.f * q6.y, -2.f * q7.y);
        v2f m2z67 = mk2(-2.f * q6.z, -2.f * q7.z), qw67 = mk2(q6.w, q7.w);
        float m2x = -2.f * qq.x, m2y = -2.f * qq.y, m2z = -2.f * qq.z, qw4 = qq.w;

        // ---- shared prepass: chunk [w*256,(w+1)*256) x 8 queries ----
        v2f r01 = mk2(3.4e38f, 3.4e38f), r23 = r01, r45 = r01, r67 = r01;
        {
            int sbase = (w << 8) + lane;
            float4 p = pts4[sbase];
#pragma unroll 1
            for (int it = 0; it < 4; ++it) {
                float4 pn;
                if (it < 3) pn = pts4[sbase + ((it + 1) << 6)];
                v2f s01, s23, s45, s67;
                D8(p, s01, s23, s45, s67)
                r01 = min2(r01, s01); r23 = min2(r23, s23);
                r45 = min2(r45, s45); r67 = min2(r67, s67);
                p = pn;
            }
        }
        {
            int pbase = (w << 6) + lane;
            pminS[0][pbase] = r01.x; pminS[1][pbase] = r01.y;
            pminS[2][pbase] = r23.x; pminS[3][pbase] = r23.y;
            pminS[4][pbase] = r45.x; pminS[5][pbase] = r45.y;
            pminS[6][pbase] = r67.x; pminS[7][pbase] = r67.y;
        }
        __syncthreads();

        // merge own query's 8 partials -> exact 64 lane-minima; truncated radix
        {
            float mn = pminS[w][lane];
#pragma unroll
            for (int c = 1; c < 8; ++c) mn = fminf(mn, pminS[w][(c << 6) + lane]);
            uint kmn = fkey(mn);
            uint P = 0x80000000u;
            for (int b = 30; b >= 15; --b) {
                uint cand = P | (1u << b);
                if ((uint)__popcll(__ballot(kmn < cand)) < 32u) P = cand;
            }
            if (lane == 0) Tsh[w] = finv(P | 0x7FFFu);
        }
        __syncthreads();
        float T0 = Tsh[0], T1 = Tsh[1], T2 = Tsh[2], T3 = Tsh[3];
        float T4 = Tsh[4], T5 = Tsh[5], T6 = Tsh[6], T7 = Tsh[7];

        // ---- mask sweep: wave w covers [w*1024,(w+1)*1024) for all 8 queries ----
        uint m0 = 0u, m1 = 0u, m2 = 0u, m3 = 0u, m4 = 0u, m5 = 0u, m6 = 0u, m7 = 0u;
        int cbase = (w << 10) + lane;
        {
            uint K = 1u;
            float4 p = pts4[cbase];
#pragma unroll 1
            for (int it = 0; it < 16; ++it) {
                float4 pn;
                if (it < 15) pn = pts4[cbase + ((it + 1) << 6)];
                v2f s01, s23, s45, s67;
                D8(p, s01, s23, s45, s67)
                m0 |= (s01.x <= T0) ? K : 0u;
                m1 |= (s01.y <= T1) ? K : 0u;
                m2 |= (s23.x <= T2) ? K : 0u;
                m3 |= (s23.y <= T3) ? K : 0u;
                m4 |= (s45.x <= T4) ? K : 0u;
                m5 |= (s45.y <= T5) ? K : 0u;
                m6 |= (s67.x <= T6) ? K : 0u;
                m7 |= (s67.y <= T7) ? K : 0u;
                K += K;
                p = pn;
            }
        }

        // ---- deterministic ballot compaction into [q][seg=w] segments ----
#define COMPACT(Q, MQ) { \
        uint cnt = 0; \
        for (;;) { \
            u64 mk = __ballot(MQ != 0u); \
            if (mk == 0ull) break; \
            bool act = (MQ != 0u); \
            uint itb = (uint)(__ffs(MQ) - 1); \
            uint pos = cnt + mbcnt64(mk); \
            if (act) { \
                if (pos < CAPSEG) spillIdx[Q][w][pos] = (uint)cbase + (itb << 6); \
                MQ &= MQ - 1u; \
            } \
            cnt += (uint)__popcll(mk); \
        } \
        if (lane == 0) segcnt[Q][w] = cnt; }

        COMPACT(0, m0) COMPACT(1, m1) COMPACT(2, m2) COMPACT(3, m3)
        COMPACT(4, m4) COMPACT(5, m5) COMPACT(6, m6) COMPACT(7, m7)
        __syncthreads();

        // ---- refine: wave w selects exact top-32 for query qbase+w ----
        uint o1, o2, o3, o4, o5, o6, o7, total;
        {
            uint a0 = min(segcnt[w][0], (uint)CAPSEG), a1 = min(segcnt[w][1], (uint)CAPSEG);
            uint a2 = min(segcnt[w][2], (uint)CAPSEG), a3 = min(segcnt[w][3], (uint)CAPSEG);
            uint a4 = min(segcnt[w][4], (uint)CAPSEG), a5 = min(segcnt[w][5], (uint)CAPSEG);
            uint a6 = min(segcnt[w][6], (uint)CAPSEG), a7 = min(segcnt[w][7], (uint)CAPSEG);
            o1 = a0; o2 = o1 + a1; o3 = o2 + a2; o4 = o3 + a3;
            o5 = o4 + a4; o6 = o5 + a5; o7 = o6 + a6; total = o7 + a7;
        }

        uint kk[8], id[8];
#pragma unroll
        for (int s = 0; s < 8; ++s) {
            kk[s] = 0xFFFFFFFFu; id[s] = 0xFFFFFFFFu;
            if ((uint)(s * 64) < total) {                   // wave-uniform guard
                uint gp = (uint)(s * 64) + (uint)lane;
                if (gp < total) {
                    uint seg = (uint)(gp >= o1) + (uint)(gp >= o2) + (uint)(gp >= o3)
                             + (uint)(gp >= o4) + (uint)(gp >= o5) + (uint)(gp >= o6)
                             + (uint)(gp >= o7);
                    uint sub = (seg == 0u) ? 0u : (seg == 1u) ? o1 : (seg == 2u) ? o2
                             : (seg == 3u) ? o3 : (seg == 4u) ? o4 : (seg == 5u) ? o5
                             : (seg == 6u) ? o6 : o7;
                    uint idx = spillIdx[w][seg][gp - sub];
                    float4 pz = pts4[idx];
                    float d2 = fmaf(m2x, pz.x, fmaf(m2y, pz.y, fmaf(m2z, pz.z, qw4 + pz.w)));
                    kk[s] = fkey(d2); id[s] = idx;
                }
            }
        }

        // Kc = key of 32nd-smallest spilled candidate (EXACT full radix)
        uint Kc = 0x80000000u;
        for (int b = 30; b >= 0; --b) {
            uint cand = Kc | (1u << b);
            uint cnt = 0;
#pragma unroll
            for (int s = 0; s < 8; ++s)
                if ((uint)(s * 64) < total) cnt += (uint)__popcll(__ballot(kk[s] < cand));
            if (cnt < 32u) Kc = cand;
        }
        uint nlt = 0, ntie = 0;
#pragma unroll
        for (int s = 0; s < 8; ++s)
            if ((uint)(s * 64) < total) {
                nlt  += (uint)__popcll(__ballot(kk[s] < Kc));
                ntie += (uint)__popcll(__ballot(kk[s] == Kc));
            }
        uint need = 32u - nlt;
        uint icut = 0xFFFFFFFFu;
        if (ntie != need) {   // tie-break by smallest index (ids unique, 13 bits)
            uint P2 = 0u;
            for (int b = 12; b >= 0; --b) {
                uint cand = P2 | (1u << b);
                uint cnt = 0;
#pragma unroll
                for (int s = 0; s < 8; ++s)
                    if ((uint)(s * 64) < total)
                        cnt += (uint)__popcll(__ballot(kk[s] == Kc && id[s] < cand));
                if (cnt < need) P2 = cand;
            }
            icut = P2;
        }

        // ballot-compacted write of the exact 32 selected indices into LDS
        uint dpos = 0;
#pragma unroll
        for (int s = 0; s < 8; ++s)
            if ((uint)(s * 64) < total) {
                bool acc = (kk[s] < Kc) || (kk[s] == Kc && id[s] <= icut);
                u64 mk = __ballot(acc);
                uint pos = dpos + mbcnt64(mk);
                if (acc) selEJ[w][pos].y = id[s];
                dpos += (uint)__popcll(mk);
            }

        // ---- fused surround branch (same wave, own query) ----
        int q = qbase + w;
        int k = lane & 31;
        uint j = selEJ[w][k].y;
        float4 pj = pts4[j];
        float dx = qq.x - pj.x, dy = qq.y - pj.y, dz = qq.z - pj.z;
        float dist = sqrtf(fmaf(dx, dx, fmaf(dy, dy, dz * dz)));
        float dmin = dist;
        for (int off = 16; off >= 1; off >>= 1) dmin = fminf(dmin, __shfl_xor(dmin, off));
        float e = expf(dmin - dist);
        float S = e;
        for (int off = 16; off >= 1; off >>= 1) S += __shfl_xor(S, off);
        if (lane < 32) selEJ[w][k].x = __float_as_uint(e);

        int d0 = lane * 2;
        float mx0 = -INFINITY, mx1 = -INFINITY;
        for (int kb = 0; kb < 32; kb += 8) {       // 8 gather loads in flight
            float ew[8];
            float2 gv[8];
#pragma unroll
            for (int jj = 0; jj < 8; ++jj) {
                uint2 ej = selEJ[w][kb + jj];
                ew[jj] = __uint_as_float(ej.x);
                gv[jj] = *(const float2*)&g[ej.y * 128u + (uint)d0];
            }
#pragma unroll
            for (int jj = 0; jj < 8; ++jj) {
                mx0 = fmaxf(mx0, ew[jj] * gv[jj].x);
                mx1 = fmaxf(mx1, ew[jj] * gv[jj].y);
            }
        }
        float inv = 1.0f / S;
        *(float2*)&F[q * 128 + d0] = make_float2(mx0 * inv, mx1 * inv);
    }
}

// ---------------------------------------------------------------------------
// out[d][n] = sum_{c<128} Wf[d][c]*F[n][c] + Wq[d]·pts[n] + bq[d]
// 16 points/block, 512 blocks (2 blocks/CU -> 8 waves/CU). Thread tile 2n x 4d.
__launch_bounds__(256)
__global__ void k_final(const float* __restrict__ F, const float* __restrict__ Wf,
                        const float* __restrict__ Wq, const float* __restrict__ bq,
                        const float4* __restrict__ pts4, float* __restrict__ out) {
    __shared__ float Fs[128 * 18];     // [k][n] padded
    __shared__ float wfs[32 * 132];    // [kk][d] padded
    int t = threadIdx.x;
    int tn = t & 7;
    int td = t >> 3;                   // 0..31
    int n0 = blockIdx.x * 16;
    int d0 = td * 4;

    {   // stage F tile via float4: 16 n x 128 k = 512 float4
        const float4* Fv = (const float4*)(F + n0 * 128);
        for (int i = t; i < 512; i += 256) {
            float4 v = Fv[i];
            int nn = i >> 5;
            int kk = (i & 31) * 4;
            Fs[(kk + 0) * 18 + nn] = v.x; Fs[(kk + 1) * 18 + nn] = v.y;
            Fs[(kk + 2) * 18 + nn] = v.z; Fs[(kk + 3) * 18 + nn] = v.w;
        }
    }

    v2f acc2[2][2];    // [n-sub][d-pair]
#pragma unroll
    for (int a = 0; a < 2; ++a)
#pragma unroll
        for (int jj = 0; jj < 2; ++jj) acc2[a][jj] = mk2(0.f, 0.f);

    for (int kc = 0; kc < 4; ++kc) {
        __syncthreads();
        for (int i = t; i < 1024; i += 256) {       // 128 d x 32 k as float4
            int d = i >> 3;
            int kkg = (i & 7) * 4;
            float4 v = *(const float4*)&Wf[d * 256 + kc * 32 + kkg];
            wfs[(kkg + 0) * 132 + d] = v.x; wfs[(kkg + 1) * 132 + d] = v.y;
            wfs[(kkg + 2) * 132 + d] = v.z; wfs[(kkg + 3) * 132 + d] = v.w;
        }
        __syncthreads();
#pragma unroll 8
        for (int kk = 0; kk < 32; ++kk) {
            int k = kc * 32 + kk;
            float2 f = *(const float2*)&Fs[k * 18 + tn * 2];
            float4 wa = *(const float4*)&wfs[kk * 132 + d0];
            v2f w0 = mk2(wa.x, wa.y), w1 = mk2(wa.z, wa.w);
            v2f fx = mk2(f.x, f.x), fy = mk2(f.y, f.y);
            acc2[0][0] = fma2(fx, w0, acc2[0][0]); acc2[1][0] = fma2(fy, w0, acc2[1][0]);
            acc2[0][1] = fma2(fx, w1, acc2[0][1]); acc2[1][1] = fma2(fy, w1, acc2[1][1]);
        }
    }

    float4 pA = pts4[n0 + tn * 2], pB = pts4[n0 + tn * 2 + 1];
#pragma unroll
    for (int jj = 0; jj < 2; ++jj) {
        int dA = d0 + 2 * jj, dB = dA + 1;
        float qa0 = Wq[dA * 3 + 0], qa1 = Wq[dA * 3 + 1], qa2 = Wq[dA * 3 + 2];
        float qb0 = Wq[dB * 3 + 0], qb1 = Wq[dB * 3 + 1], qb2 = Wq[dB * 3 + 2];
        float ba = bq[dA], bb = bq[dB];
        float oA0 = acc2[0][jj].x + fmaf(qa0, pA.x, fmaf(qa1, pA.y, fmaf(qa2, pA.z, ba)));
        float oA1 = acc2[1][jj].x + fmaf(qa0, pB.x, fmaf(qa1, pB.y, fmaf(qa2, pB.z, ba)));
        float oB0 = acc2[0][jj].y + fmaf(qb0, pA.x, fmaf(qb1, pA.y, fmaf(qb2, pA.z, bb)));
        float oB1 = acc2[1][jj].y + fmaf(qb0, pB.x, fmaf(qb1, pB.y, fmaf(qb2, pB.z, bb)));
        *(float2*)&out[dA * NPTS + n0 + tn * 2] = make_float2(oA0, oA1);
        *(float2*)&out[dB * NPTS + n0 + tn * 2] = make_float2(oB0, oB1);
    }
}

// ---------------------------------------------------------------------------
extern "C" void kernel_launch(void* const* d_in, const int* in_sizes, int n_in,
                              void* d_out, int out_size, void* d_ws, size_t ws_size,
                              hipStream_t stream) {
    const float* img_feat = (const float*)d_in[0];
    const float* cloud    = (const float*)d_in[1];
    const float* W1  = (const float*)d_in[2];
    const float* b1  = (const float*)d_in[3];
    const float* W2  = (const float*)d_in[4];
    const float* b2  = (const float*)d_in[5];
    const float* Wp1 = (const float*)d_in[6];
    const float* bp1 = (const float*)d_in[7];
    const float* Wp2 = (const float*)d_in[8];
    const float* bp2 = (const float*)d_in[9];
    const float* Wf  = (const float*)d_in[10];
    const float* bf  = (const float*)d_in[11];
    float* out = (float*)d_out;

    char* ws = (char*)d_ws;
    float4* pts4 = (float4*)(ws + OFF_PTS4);
    uint* ctr  = (uint*)(ws + OFF_CTR);
    float* Wq  = (float*)(ws + OFF_WQ);
    float* bq  = (float*)(ws + OFF_BQ);
    float* g   = (float*)(ws + OFF_G);
    float* F   = (float*)(ws + OFF_F);

    k_prep_gfeat<<<545, 256, 0, stream>>>(cloud, img_feat, W1, b1, W2, b2,
                                          Wp1, bp1, Wp2, bp2, Wf, bf,
                                          pts4, Wq, bq, g, ctr);
    k_knn<<<1024, 512, 0, stream>>>(pts4, g, F, ctr);
    k_final<<<NPTS / 32 * 2, 256, 0, stream>>>(F, Wf, Wq, bq, pts4, out);
}

// Round 19
// 73.765 us; speedup vs baseline: 1.2399x; 1.2399x over previous
//
#include <hip/hip_runtime.h>
#include <math.h>

#define NPTS 8192
#define KNN 32

typedef unsigned int uint;
typedef unsigned long long u64;
typedef float v2f __attribute__((ext_vector_type(2)));

#if __has_builtin(__builtin_elementwise_fma)
__device__ __forceinline__ v2f fma2(v2f a, v2f b, v2f c) {
    return __builtin_elementwise_fma(a, b, c);
}
#else
__device__ __forceinline__ v2f fma2(v2f a, v2f b, v2f c) {
    v2f r; r.x = fmaf(a.x, b.x, c.x); r.y = fmaf(a.y, b.y, c.y); return r;
}
#endif
#if __has_builtin(__builtin_elementwise_min)
__device__ __forceinline__ v2f min2(v2f a, v2f b) {
    return __builtin_elementwise_min(a, b);
}
#else
__device__ __forceinline__ v2f min2(v2f a, v2f b) {
    v2f r; r.x = fminf(a.x, b.x); r.y = fminf(a.y, b.y); return r;
}
#endif
__device__ __forceinline__ v2f mk2(float a, float b) { v2f r; r.x = a; r.y = b; return r; }

// ---- workspace layout (bytes) ----
#define OFF_PTS4 0                      // float4[N]            131072
#define OFF_WQ   147968                 // float[128*3]         1536  (Wf_pc@Wpc)
#define OFF_BQ   149504                 // float[128]           512   (Wf_pc@bpc+bf)
#define OFF_G    150016                 // float[N*128]         4194304
#define OFF_F    5392896                // float[N*128] row-major sur only 4194304

__device__ __forceinline__ uint fkey(float d) {
    uint bits = __float_as_uint(d);
    return bits ^ (0x80000000u | (uint)((int)bits >> 31));  // monotone sortable
}
__device__ __forceinline__ float finv(uint key) {
    uint bits = (key & 0x80000000u) ? (key ^ 0x80000000u) : ~key;
    return __uint_as_float(bits);
}
__device__ __forceinline__ uint mbcnt64(u64 m) {
    uint lo = __builtin_amdgcn_mbcnt_lo((uint)m, 0u);
    return __builtin_amdgcn_mbcnt_hi((uint)(m >> 32), lo);
}

// ---------------------------------------------------------------------------
// ONE preprocessing kernel, zero intra-kernel dependencies:
//   blocks 0..31   : pts4 = (x,y,z,|p|^2)
//   block  32      : Wq = Wf[:,128:]@(Wp2@Wp1), bq = Wf[:,128:]@(Wp2@bp1+bp2)+bf
//   blocks 33..544 : g[n][:] two-stage from raw W1/b1/W2/b2 (16 points/block)
__launch_bounds__(256)
__global__ void k_prep_gfeat(const float* __restrict__ cloud, const float* __restrict__ img_feat,
                             const float* __restrict__ W1, const float* __restrict__ b1,
                             const float* __restrict__ W2, const float* __restrict__ b2,
                             const float* __restrict__ Wp1, const float* __restrict__ bp1,
                             const float* __restrict__ Wp2, const float* __restrict__ bp2,
                             const float* __restrict__ Wf, const float* __restrict__ bf,
                             float4* __restrict__ pts4, float* __restrict__ Wq,
                             float* __restrict__ bq, float* __restrict__ g) {
    int bid = blockIdx.x;
    int t = threadIdx.x;
    if (bid < 32) {
        int n = bid * 256 + t;
        float x = cloud[n * 3 + 0], y = cloud[n * 3 + 1], z = cloud[n * 3 + 2];
        float sq = fmaf(x, x, fmaf(y, y, z * z));
        pts4[n] = make_float4(x, y, z, sq);
        return;
    }
    if (bid == 32) {
        __shared__ float wpcS[384];
        __shared__ float bpcS[128];
        for (int i = t; i < 384; i += 256) {
            int o = i / 3, c = i - o * 3;
            float a = 0.f;
            for (int u = 0; u < 64; ++u) a = fmaf(Wp2[o * 64 + u], Wp1[u * 3 + c], a);
            wpcS[i] = a;
        }
        if (t < 128) {
            float a = bp2[t];
            for (int u = 0; u < 64; ++u) a = fmaf(Wp2[t * 64 + u], bp1[u], a);
            bpcS[t] = a;
        }
        __syncthreads();
        for (int i = t; i < 384; i += 256) {
            int d = i / 3, c = i - d * 3;
            float a = 0.f;
            for (int o = 0; o < 128; ++o) a = fmaf(Wf[d * 256 + 128 + o], wpcS[o * 3 + c], a);
            Wq[i] = a;
        }
        if (t < 128) {
            float a = bf[t];
            for (int o = 0; o < 128; ++o) a = fmaf(Wf[t * 256 + 128 + o], bpcS[o], a);
            bq[t] = a;
        }
        return;
    }
    // ---- gfeat: 16 points, two-stage; W2 staged into LDS (coalesced) with
    // XOR-swizzled float4 blocks so stage-2 row reads are ds_read_b128.
    {
        __shared__ float ftT[16][36];   // [n][c]
        __shared__ float hS[16][68];    // [n][o]
        __shared__ float w2S[128 * 64]; // [d][og^...]   32 KB
        int n0 = (bid - 33) * 16;

        if (t < 128) {                  // 32c x 16n, one float4 per thread
            int c = t >> 2, ng = (t & 3) * 4;
            float4 v = *(const float4*)&img_feat[c * NPTS + n0 + ng];
            ftT[ng + 0][c] = v.x; ftT[ng + 1][c] = v.y;
            ftT[ng + 2][c] = v.z; ftT[ng + 3][c] = v.w;
        }
        {   // W2 bounce: 2048 float4, coalesced global, swizzled LDS
            const float4* W2v = (const float4*)W2;
            for (int i = t; i < 2048; i += 256) {
                float4 v = W2v[i];
                int dd = i >> 4, og = i & 15;
                *(float4*)&w2S[dd * 64 + ((og ^ (dd & 15)) << 2)] = v;
            }
        }
        __syncthreads();

        // stage 1: h[n][o] = b1[o] + sum_c W1[o][c] * ft[n][c]
        {
            int n = t & 15, ob = t >> 4;           // ob in 0..15
            v2f fr[16];
#pragma unroll
            for (int c4 = 0; c4 < 8; ++c4) {
                float4 fv = *(const float4*)&ftT[n][c4 * 4];
                fr[2 * c4 + 0] = mk2(fv.x, fv.y);
                fr[2 * c4 + 1] = mk2(fv.z, fv.w);
            }
#pragma unroll
            for (int r = 0; r < 4; ++r) {
                int o = ob + r * 16;
                v2f acc = mk2(b1[o], 0.f);
                const float4* w1r = (const float4*)&W1[o * 32];
#pragma unroll
                for (int c4 = 0; c4 < 8; ++c4) {
                    float4 wv = w1r[c4];
                    acc = fma2(mk2(wv.x, wv.y), fr[2 * c4 + 0], acc);
                    acc = fma2(mk2(wv.z, wv.w), fr[2 * c4 + 1], acc);
                }
                hS[n][o] = acc.x + acc.y;
            }
        }
        __syncthreads();

        // stage 2: g[n][d] = b2[d] + sum_o W2[d][o] * h[n][o]
        {
            int d = t & 127, grp = t >> 7;
            v2f w2r[32];
#pragma unroll
            for (int o4 = 0; o4 < 16; ++o4) {
                float4 wv = *(const float4*)&w2S[d * 64 + ((o4 ^ (d & 15)) << 2)];
                w2r[2 * o4 + 0] = mk2(wv.x, wv.y);
                w2r[2 * o4 + 1] = mk2(wv.z, wv.w);
            }
            float b2d = b2[d];
#pragma unroll
            for (int nl = grp * 8; nl < grp * 8 + 8; ++nl) {
                v2f acc = mk2(b2d, 0.f);
#pragma unroll
                for (int o4 = 0; o4 < 16; ++o4) {
                    float4 hv = *(const float4*)&hS[nl][o4 * 4];   // broadcast
                    acc = fma2(w2r[2 * o4 + 0], mk2(hv.x, hv.y), acc);
                    acc = fma2(w2r[2 * o4 + 1], mk2(hv.z, hv.w), acc);
                }
                g[(n0 + nl) * 128 + d] = acc.x + acc.y;
            }
        }
    }
}

// ---------------------------------------------------------------------------
// Exact KNN + fused surround branch, v5: 8 queries / block (512 thr, 8 waves).
// Shared prepass + truncated-threshold radix (16 steps, ones-filled: invariant
// count(kmn <= P|0x7FFF) >= 32 holds by induction -> T still guarantees >= 32
// candidates; exact select downstream unchanged). 16-bit mask sweep, ballot
// compaction, exact radix select, fused epilogue (8-deep gather batches).
#define CAPSEG 64
__launch_bounds__(512, 8)
__global__ void k_knn(const float4* __restrict__ pts4, const float* __restrict__ g,
                      float* __restrict__ F) {
    __shared__ float pminS[8][512];           // [q][wave*64+lane]   16 KB
    __shared__ uint spillIdx[8][8][CAPSEG];   // [q][seg][slot]      16 KB
    __shared__ uint segcnt[8][8];             // [q][seg]
    __shared__ float Tsh[8];
    __shared__ uint2 selEJ[8][32];            // per query: (.x = e bits, .y = idx)

    int t = threadIdx.x, w = t >> 6, lane = t & 63;
    int qbase = blockIdx.x * 8;
    float4 q0 = pts4[qbase + 0], q1 = pts4[qbase + 1], q2 = pts4[qbase + 2], q3 = pts4[qbase + 3];
    float4 q4 = pts4[qbase + 4], q5 = pts4[qbase + 5], q6 = pts4[qbase + 6], q7 = pts4[qbase + 7];
    float4 qq = pts4[qbase + w];              // own query

    // packed pair constants: d2 = fma(-2qx,px, fma(-2qy,py, fma(-2qz,pz, qw+pw)))
    v2f m2x01 = mk2(-2.f * q0.x, -2.f * q1.x), m2y01 = mk2(-2.f * q0.y, -2.f * q1.y);
    v2f m2z01 = mk2(-2.f * q0.z, -2.f * q1.z), qw01 = mk2(q0.w, q1.w);
    v2f m2x23 = mk2(-2.f * q2.x, -2.f * q3.x), m2y23 = mk2(-2.f * q2.y, -2.f * q3.y);
    v2f m2z23 = mk2(-2.f * q2.z, -2.f * q3.z), qw23 = mk2(q2.w, q3.w);
    v2f m2x45 = mk2(-2.f * q4.x, -2.f * q5.x), m2y45 = mk2(-2.f * q4.y, -2.f * q5.y);
    v2f m2z45 = mk2(-2.f * q4.z, -2.f * q5.z), qw45 = mk2(q4.w, q5.w);
    v2f m2x67 = mk2(-2.f * q6.x, -2.f * q7.x), m2y67 = mk2(-2.f * q6.y, -2.f * q7.y);
    v2f m2z67 = mk2(-2.f * q6.z, -2.f * q7.z), qw67 = mk2(q6.w, q7.w);
    float m2x = -2.f * qq.x, m2y = -2.f * qq.y, m2z = -2.f * qq.z, qw4 = qq.w;

#define D8(P, S01, S23, S45, S67) { \
    v2f pw2 = mk2((P).w, (P).w), pz2 = mk2((P).z, (P).z); \
    v2f py2 = mk2((P).y, (P).y), px2 = mk2((P).x, (P).x); \
    S01 = qw01 + pw2; S01 = fma2(m2z01, pz2, S01); S01 = fma2(m2y01, py2, S01); S01 = fma2(m2x01, px2, S01); \
    S23 = qw23 + pw2; S23 = fma2(m2z23, pz2, S23); S23 = fma2(m2y23, py2, S23); S23 = fma2(m2x23, px2, S23); \
    S45 = qw45 + pw2; S45 = fma2(m2z45, pz2, S45); S45 = fma2(m2y45, py2, S45); S45 = fma2(m2x45, px2, S45); \
    S67 = qw67 + pw2; S67 = fma2(m2z67, pz2, S67); S67 = fma2(m2y67, py2, S67); S67 = fma2(m2x67, px2, S67); }

    // ---- shared prepass: chunk [w*256,(w+1)*256) x 8 queries ----
    v2f r01 = mk2(3.4e38f, 3.4e38f), r23 = r01, r45 = r01, r67 = r01;
    {
        int sbase = (w << 8) + lane;
        float4 p = pts4[sbase];
#pragma unroll 1
        for (int it = 0; it < 4; ++it) {
            float4 pn;
            if (it < 3) pn = pts4[sbase + ((it + 1) << 6)];
            v2f s01, s23, s45, s67;
            D8(p, s01, s23, s45, s67)
            r01 = min2(r01, s01); r23 = min2(r23, s23);
            r45 = min2(r45, s45); r67 = min2(r67, s67);
            p = pn;
        }
    }
    {
        int pbase = (w << 6) + lane;
        pminS[0][pbase] = r01.x; pminS[1][pbase] = r01.y;
        pminS[2][pbase] = r23.x; pminS[3][pbase] = r23.y;
        pminS[4][pbase] = r45.x; pminS[5][pbase] = r45.y;
        pminS[6][pbase] = r67.x; pminS[7][pbase] = r67.y;
    }
    __syncthreads();

    // merge own query's 8 partials -> exact 64 lane-minima; truncated radix
    {
        float mn = pminS[w][lane];
#pragma unroll
        for (int c = 1; c < 8; ++c) mn = fminf(mn, pminS[w][(c << 6) + lane]);
        uint kmn = fkey(mn);
        uint P = 0x80000000u;
        for (int b = 30; b >= 15; --b) {
            uint cand = P | (1u << b);
            if ((uint)__popcll(__ballot(kmn < cand)) < 32u) P = cand;
        }
        if (lane == 0) Tsh[w] = finv(P | 0x7FFFu);
    }
    __syncthreads();
    float T0 = Tsh[0], T1 = Tsh[1], T2 = Tsh[2], T3 = Tsh[3];
    float T4 = Tsh[4], T5 = Tsh[5], T6 = Tsh[6], T7 = Tsh[7];

    // ---- mask sweep: wave w covers [w*1024,(w+1)*1024) for all 8 queries ----
    uint m0 = 0u, m1 = 0u, m2 = 0u, m3 = 0u, m4 = 0u, m5 = 0u, m6 = 0u, m7 = 0u;
    int cbase = (w << 10) + lane;
    {
        uint K = 1u;
        float4 p = pts4[cbase];
#pragma unroll 1
        for (int it = 0; it < 16; ++it) {
            float4 pn;
            if (it < 15) pn = pts4[cbase + ((it + 1) << 6)];
            v2f s01, s23, s45, s67;
            D8(p, s01, s23, s45, s67)
            m0 |= (s01.x <= T0) ? K : 0u;
            m1 |= (s01.y <= T1) ? K : 0u;
            m2 |= (s23.x <= T2) ? K : 0u;
            m3 |= (s23.y <= T3) ? K : 0u;
            m4 |= (s45.x <= T4) ? K : 0u;
            m5 |= (s45.y <= T5) ? K : 0u;
            m6 |= (s67.x <= T6) ? K : 0u;
            m7 |= (s67.y <= T7) ? K : 0u;
            K += K;
            p = pn;
        }
    }

    // ---- deterministic ballot compaction into [q][seg=w] segments ----
#define COMPACT(Q, MQ) { \
    uint cnt = 0; \
    for (;;) { \
        u64 mk = __ballot(MQ != 0u); \
        if (mk == 0ull) break; \
        bool act = (MQ != 0u); \
        uint itb = (uint)(__ffs(MQ) - 1); \
        uint pos = cnt + mbcnt64(mk); \
        if (act) { \
            if (pos < CAPSEG) spillIdx[Q][w][pos] = (uint)cbase + (itb << 6); \
            MQ &= MQ - 1u; \
        } \
        cnt += (uint)__popcll(mk); \
    } \
    if (lane == 0) segcnt[Q][w] = cnt; }

    COMPACT(0, m0) COMPACT(1, m1) COMPACT(2, m2) COMPACT(3, m3)
    COMPACT(4, m4) COMPACT(5, m5) COMPACT(6, m6) COMPACT(7, m7)
    __syncthreads();

    // ---- refine: wave w selects exact top-32 for query qbase+w ----
    uint o1, o2, o3, o4, o5, o6, o7, total;
    {
        uint a0 = min(segcnt[w][0], (uint)CAPSEG), a1 = min(segcnt[w][1], (uint)CAPSEG);
        uint a2 = min(segcnt[w][2], (uint)CAPSEG), a3 = min(segcnt[w][3], (uint)CAPSEG);
        uint a4 = min(segcnt[w][4], (uint)CAPSEG), a5 = min(segcnt[w][5], (uint)CAPSEG);
        uint a6 = min(segcnt[w][6], (uint)CAPSEG), a7 = min(segcnt[w][7], (uint)CAPSEG);
        o1 = a0; o2 = o1 + a1; o3 = o2 + a2; o4 = o3 + a3;
        o5 = o4 + a4; o6 = o5 + a5; o7 = o6 + a6; total = o7 + a7;
    }

    uint kk[8], id[8];
#pragma unroll
    for (int s = 0; s < 8; ++s) {
        kk[s] = 0xFFFFFFFFu; id[s] = 0xFFFFFFFFu;
        if ((uint)(s * 64) < total) {                       // wave-uniform guard
            uint gp = (uint)(s * 64) + (uint)lane;
            if (gp < total) {
                uint seg = (uint)(gp >= o1) + (uint)(gp >= o2) + (uint)(gp >= o3)
                         + (uint)(gp >= o4) + (uint)(gp >= o5) + (uint)(gp >= o6)
                         + (uint)(gp >= o7);
                uint sub = (seg == 0u) ? 0u : (seg == 1u) ? o1 : (seg == 2u) ? o2
                         : (seg == 3u) ? o3 : (seg == 4u) ? o4 : (seg == 5u) ? o5
                         : (seg == 6u) ? o6 : o7;
                uint idx = spillIdx[w][seg][gp - sub];
                float4 pz = pts4[idx];
                float d2 = fmaf(m2x, pz.x, fmaf(m2y, pz.y, fmaf(m2z, pz.z, qw4 + pz.w)));
                kk[s] = fkey(d2); id[s] = idx;
            }
        }
    }

    // Kc = key of 32nd-smallest spilled candidate (EXACT full radix)
    uint Kc = 0x80000000u;
    for (int b = 30; b >= 0; --b) {
        uint cand = Kc | (1u << b);
        uint cnt = 0;
#pragma unroll
        for (int s = 0; s < 8; ++s)
            if ((uint)(s * 64) < total) cnt += (uint)__popcll(__ballot(kk[s] < cand));
        if (cnt < 32u) Kc = cand;
    }
    uint nlt = 0, ntie = 0;
#pragma unroll
    for (int s = 0; s < 8; ++s)
        if ((uint)(s * 64) < total) {
            nlt  += (uint)__popcll(__ballot(kk[s] < Kc));
            ntie += (uint)__popcll(__ballot(kk[s] == Kc));
        }
    uint need = 32u - nlt;
    uint icut = 0xFFFFFFFFu;
    if (ntie != need) {   // tie-break by smallest index (ids unique, 13 bits)
        uint P2 = 0u;
        for (int b = 12; b >= 0; --b) {
            uint cand = P2 | (1u << b);
            uint cnt = 0;
#pragma unroll
            for (int s = 0; s < 8; ++s)
                if ((uint)(s * 64) < total)
                    cnt += (uint)__popcll(__ballot(kk[s] == Kc && id[s] < cand));
            if (cnt < need) P2 = cand;
        }
        icut = P2;
    }

    // ballot-compacted write of the exact 32 selected indices into LDS
    uint dpos = 0;
#pragma unroll
    for (int s = 0; s < 8; ++s)
        if ((uint)(s * 64) < total) {
            bool acc = (kk[s] < Kc) || (kk[s] == Kc && id[s] <= icut);
            u64 mk = __ballot(acc);
            uint pos = dpos + mbcnt64(mk);
            if (acc) selEJ[w][pos].y = id[s];
            dpos += (uint)__popcll(mk);
        }

    // ---- fused surround branch (same wave, own query) ----
    int q = qbase + w;
    int k = lane & 31;
    uint j = selEJ[w][k].y;
    float4 pj = pts4[j];
    float dx = qq.x - pj.x, dy = qq.y - pj.y, dz = qq.z - pj.z;
    float dist = sqrtf(fmaf(dx, dx, fmaf(dy, dy, dz * dz)));
    float dmin = dist;
    for (int off = 16; off >= 1; off >>= 1) dmin = fminf(dmin, __shfl_xor(dmin, off));
    float e = expf(dmin - dist);
    float S = e;
    for (int off = 16; off >= 1; off >>= 1) S += __shfl_xor(S, off);
    if (lane < 32) selEJ[w][k].x = __float_as_uint(e);

    int d0 = lane * 2;
    float mx0 = -INFINITY, mx1 = -INFINITY;
    for (int kb = 0; kb < 32; kb += 8) {       // 8 gather loads in flight
        float ew[8];
        float2 gv[8];
#pragma unroll
        for (int jj = 0; jj < 8; ++jj) {
            uint2 ej = selEJ[w][kb + jj];
            ew[jj] = __uint_as_float(ej.x);
            gv[jj] = *(const float2*)&g[ej.y * 128u + (uint)d0];
        }
#pragma unroll
        for (int jj = 0; jj < 8; ++jj) {
            mx0 = fmaxf(mx0, ew[jj] * gv[jj].x);
            mx1 = fmaxf(mx1, ew[jj] * gv[jj].y);
        }
    }
    float inv = 1.0f / S;
    *(float2*)&F[q * 128 + d0] = make_float2(mx0 * inv, mx1 * inv);
}

// ---------------------------------------------------------------------------
// out[d][n] = sum_{c<128} Wf[d][c]*F[n][c] + Wq[d]·pts[n] + bq[d]
// 16 points/block, 512 blocks (2 blocks/CU -> 8 waves/CU). Thread tile 2n x 4d.
__launch_bounds__(256)
__global__ void k_final(const float* __restrict__ F, const float* __restrict__ Wf,
                        const float* __restrict__ Wq, const float* __restrict__ bq,
                        const float4* __restrict__ pts4, float* __restrict__ out) {
    __shared__ float Fs[128 * 18];     // [k][n] padded
    __shared__ float wfs[32 * 132];    // [kk][d] padded
    int t = threadIdx.x;
    int tn = t & 7;
    int td = t >> 3;                   // 0..31
    int n0 = blockIdx.x * 16;
    int d0 = td * 4;

    {   // stage F tile via float4: 16 n x 128 k = 512 float4
        const float4* Fv = (const float4*)(F + n0 * 128);
        for (int i = t; i < 512; i += 256) {
            float4 v = Fv[i];
            int nn = i >> 5;
            int kk = (i & 31) * 4;
            Fs[(kk + 0) * 18 + nn] = v.x; Fs[(kk + 1) * 18 + nn] = v.y;
            Fs[(kk + 2) * 18 + nn] = v.z; Fs[(kk + 3) * 18 + nn] = v.w;
        }
    }

    v2f acc2[2][2];    // [n-sub][d-pair]
#pragma unroll
    for (int a = 0; a < 2; ++a)
#pragma unroll
        for (int jj = 0; jj < 2; ++jj) acc2[a][jj] = mk2(0.f, 0.f);

    for (int kc = 0; kc < 4; ++kc) {
        __syncthreads();
        for (int i = t; i < 1024; i += 256) {       // 128 d x 32 k as float4
            int d = i >> 3;
            int kkg = (i & 7) * 4;
            float4 v = *(const float4*)&Wf[d * 256 + kc * 32 + kkg];
            wfs[(kkg + 0) * 132 + d] = v.x; wfs[(kkg + 1) * 132 + d] = v.y;
            wfs[(kkg + 2) * 132 + d] = v.z; wfs[(kkg + 3) * 132 + d] = v.w;
        }
        __syncthreads();
#pragma unroll 8
        for (int kk = 0; kk < 32; ++kk) {
            int k = kc * 32 + kk;
            float2 f = *(const float2*)&Fs[k * 18 + tn * 2];
            float4 wa = *(const float4*)&wfs[kk * 132 + d0];
            v2f w0 = mk2(wa.x, wa.y), w1 = mk2(wa.z, wa.w);
            v2f fx = mk2(f.x, f.x), fy = mk2(f.y, f.y);
            acc2[0][0] = fma2(fx, w0, acc2[0][0]); acc2[1][0] = fma2(fy, w0, acc2[1][0]);
            acc2[0][1] = fma2(fx, w1, acc2[0][1]); acc2[1][1] = fma2(fy, w1, acc2[1][1]);
        }
    }

    float4 pA = pts4[n0 + tn * 2], pB = pts4[n0 + tn * 2 + 1];
#pragma unroll
    for (int jj = 0; jj < 2; ++jj) {
        int dA = d0 + 2 * jj, dB = dA + 1;
        float qa0 = Wq[dA * 3 + 0], qa1 = Wq[dA * 3 + 1], qa2 = Wq[dA * 3 + 2];
        float qb0 = Wq[dB * 3 + 0], qb1 = Wq[dB * 3 + 1], qb2 = Wq[dB * 3 + 2];
        float ba = bq[dA], bb = bq[dB];
        float oA0 = acc2[0][jj].x + fmaf(qa0, pA.x, fmaf(qa1, pA.y, fmaf(qa2, pA.z, ba)));
        float oA1 = acc2[1][jj].x + fmaf(qa0, pB.x, fmaf(qa1, pB.y, fmaf(qa2, pB.z, ba)));
        float oB0 = acc2[0][jj].y + fmaf(qb0, pA.x, fmaf(qb1, pA.y, fmaf(qb2, pA.z, bb)));
        float oB1 = acc2[1][jj].y + fmaf(qb0, pB.x, fmaf(qb1, pB.y, fmaf(qb2, pB.z, bb)));
        *(float2*)&out[dA * NPTS + n0 + tn * 2] = make_float2(oA0, oA1);
        *(float2*)&out[dB * NPTS + n0 + tn * 2] = make_float2(oB0, oB1);
    }
}

// ---------------------------------------------------------------------------
extern "C" void kernel_launch(void* const* d_in, const int* in_sizes, int n_in,
                              void* d_out, int out_size, void* d_ws, size_t ws_size,
                              hipStream_t stream) {
    const float* img_feat = (const float*)d_in[0];
    const float* cloud    = (const float*)d_in[1];
    const float* W1  = (const float*)d_in[2];
    const float* b1  = (const float*)d_in[3];
    const float* W2  = (const float*)d_in[4];
    const float* b2  = (const float*)d_in[5];
    const float* Wp1 = (const float*)d_in[6];
    const float* bp1 = (const float*)d_in[7];
    const float* Wp2 = (const float*)d_in[8];
    const float* bp2 = (const float*)d_in[9];
    const float* Wf  = (const float*)d_in[10];
    const float* bf  = (const float*)d_in[11];
    float* out = (float*)d_out;

    char* ws = (char*)d_ws;
    float4* pts4 = (float4*)(ws + OFF_PTS4);
    float* Wq  = (float*)(ws + OFF_WQ);
    float* bq  = (float*)(ws + OFF_BQ);
    float* g   = (float*)(ws + OFF_G);
    float* F   = (float*)(ws + OFF_F);

    k_prep_gfeat<<<545, 256, 0, stream>>>(cloud, img_feat, W1, b1, W2, b2,
                                          Wp1, bp1, Wp2, bp2, Wf, bf,
                                          pts4, Wq, bq, g);
    k_knn<<<NPTS / 8, 512, 0, stream>>>(pts4, g, F);
    k_final<<<NPTS / 32 * 2, 256, 0, stream>>>(F, Wf, Wq, bq, pts4, out);
}